// Round 22
// baseline (249.973 us; speedup 1.0000x reference)
//
#include <hip/hip_runtime.h>

typedef _Float16 half8 __attribute__((ext_vector_type(8)));
typedef float floatx4 __attribute__((ext_vector_type(4)));

constexpr int Bn = 16, Cn = 256, Hn = 64, Wn = 96;
constexpr int HW = Hn * Wn;          // 6144
constexpr int Dn = 21, ND = Dn * Dn; // 441
constexpr int PH = Hn + 40;          // 104
constexpr int PW = Wn + 40;          // 136
constexpr int PHW = PH * PW;         // 14144
// pass-2 tile: 8 x 32
constexpr int TY = 8, TX = 32;
constexpr int NTY = Hn / TY;         // 8
constexpr int NTX = Wn / TX;         // 3
constexpr int NJ = (TX + 40) / 2;    // 36 window cols per parity
constexpr int GP = 506;              // G pitch f16 (NNc max 504)
// SMEM union: stage 8 waves x 8KB = 65,536 B; G 2x64x506x2 = 129,536 B
constexpr int SMEM_BYTES = 129536;   // -> 1 wg/CU (8 waves)
// f2t2 layout [b][ks:8][qb:2][py:104][cx:68][32ch f16]
constexpr size_t QB_STRIDE  = (size_t)PH * 68 * 64;      // 452,608 B
constexpr size_t KS_STRIDE  = 2 * QB_STRIDE;             // 905,216 B
constexpr size_t B2_STRIDE  = 8 * KS_STRIDE;             // 7,241,728 B

constexpr size_t F2T_BYTES = (size_t)Bn * B2_STRIDE;     // 115,867,648
constexpr size_t WS_NEEDED = F2T_BYTES;

constexpr int F2_BLKS = Bn * (PHW / 64);   // 3536

// ---------------- pass 1: f2 only -> f16 K-slice-major padded -------------
// (f1 transpose removed: corr17 reads A directly from f1 -- saves ~150MB
// of tconv traffic; each f1t pixel was only read back 2x anyway)
__global__ __launch_bounds__(256)
void tconv_f2(const float* __restrict__ f2, _Float16* __restrict__ f2t2) {
  const int blk = blockIdx.x;
  const int t = threadIdx.x;
  const int pxl = t >> 2;            // 0..63
  const int g = t & 3;
  const int b = blk / (PHW / 64);
  const int ppx = (blk % (PHW / 64)) * 64 + pxl;
  const int py = ppx / PW;
  const int px = ppx - py * PW;
  const int qb = px & 1;
  const int cx = px >> 1;
  const int yy = py - 20, xx = px - 20;
  const bool valid = (yy >= 0) & (yy < Hn) & (xx >= 0) & (xx < Wn);
  const float* src = f2 + (size_t)b * Cn * HW + (valid ? (yy * Wn + xx) : 0);
#pragma unroll
  for (int h = 0; h < 2; ++h) {
    const int ks = g + h * 4;
    _Float16* dst = (_Float16*)((char*)f2t2 + (size_t)b * B2_STRIDE
                                + (size_t)ks * KS_STRIDE + (size_t)qb * QB_STRIDE
                                + ((size_t)py * 68 + cx) * 64);
#pragma unroll
    for (int q = 0; q < 4; ++q) {
      half8 v;
#pragma unroll
      for (int k = 0; k < 8; ++k) {
        const float f = src[(size_t)(ks * 32 + q * 8 + k) * HW];
        v[k] = (_Float16)(valid ? f : 0.0f);
      }
      *(half8*)(dst + q * 8) = v;
    }
  }
}

// global->LDS DMA; lds offset raw int (SMEM at LDS offset 0), uniform (r8)
#define GLLDS(gp, lo) \
  __builtin_amdgcn_global_load_lds( \
      (const __attribute__((address_space(1))) void*)(gp), \
      (__attribute__((address_space(3))) void*)(uintptr_t)(lo), 16, 0, 0)
// asm ds_read: opaque to the LDS-DMA alias tracker (counted-vmcnt pipeline)
#define DSREAD(dst, addr, OFFSTR) \
  asm volatile("ds_read_b128 %0, %1 offset:" OFFSTR : "=v"(dst) : "v"(addr));
// asm scalar A-load: 32-bit voffset + SGPR base; m-tile via literal offset
#define GLD(dst, voff, sb, OFFSTR) \
  asm volatile("global_load_dword %0, %1, %2 offset:" OFFSTR \
               : "=v"(dst) : "v"(voff), "s"(sb));

// ---------------- pass 2: 8x32 pipelined MFMA, A direct from f1 -----------
// corr15 (2-deep; r21: 3-deep null) with A loaded straight from f1 (f32
// BCHW) via 32 scalar saddr asm loads per even stage (channels HW-strided),
// raw f32 double-buffered, converted RNE->f16 after the counted wait
// (bit-identical math to the old tconv path). Issue sizes 36/4 ->
// waits alternate vmcnt(4)/vmcnt(36); max outstanding 40 <= 63.
__global__ __launch_bounds__(512, 2)
void corr17(const float* __restrict__ f1, const _Float16* __restrict__ f2t2,
            float* __restrict__ out) {
  __shared__ __align__(16) char SMEM[SMEM_BYTES];

  // bijective XCD swizzle: 1536 wgs = 8 XCDs x 192 contiguous
  int bid = (int)blockIdx.x;
  bid = (bid & 7) * 192 + (bid >> 3);
  const int tx = bid % NTX;
  int tmp = bid / NTX;
  const int ty = tmp % NTY;
  tmp /= NTY;
  const int qa = tmp & 1;
  tmp >>= 1;
  const int chunk = tmp & 1;
  const int b = tmp >> 1;
  const int y0 = ty * TY, x0 = tx * TX;

  // dy chunks (11,10): dyLo 0,11; window rows = r+3
  const int r = chunk ? 10 : 11;
  const int dyLo = chunk ? 11 : 0;
  const int rows = r + 3;                 // 14 / 13
  const int NNc = rows * NJ;              // 504 / 468 window slots per qb
  const int ndch = r * Dn;                // 231 / 210

  const int t = threadIdx.x;
  const int lane = t & 63;
  const int wave = t >> 6;                // 0..7
  const int l15 = lane & 15;
  const int lk = lane >> 4;
  const int qbR = wave >> 2;              // waves 0-3 -> qb0; 4-7 -> qb1
  const int w4 = wave & 3;                // n-quarter: slots [w4*128, +128)

  const char* f2base = (const char*)f2t2 + (size_t)b * B2_STRIDE
                       + (size_t)qbR * QB_STRIDE;
  const float* f1b = f1 + (size_t)b * Cn * HW;  // SGPR base for A loads
  const float invc = 1.0f / 256.0f;

  // wave-private stage region: 8KB (2 x 4KB buffers), linear dest
  const unsigned wdest = __builtin_amdgcn_readfirstlane((unsigned)(wave * 8192));

  // B DMA source offsets (ks=0): DMA u covers slots s = w4*128 + u*16 +
  // (lane>>2); position p'=lane&3 stores SOURCE quarter q=(p'-(s>>1))&3
  // (rule #21: rotation via permuted global source, LDS dest linear)
  unsigned soff[8];
#pragma unroll
  for (int u = 0; u < 8; ++u) {
    int s = w4 * 128 + u * 16 + (lane >> 2);
    if (s >= NNc) s = 0;                  // clamp: dup load, deposit guarded
    const int q = ((lane & 3) - (s >> 1)) & 3;
    const int row = s / NJ, col = s % NJ;
    const int py = y0 + qa + 2 * (row + dyLo);
    soff[u] = (unsigned)(((py * 68 + (x0 >> 1) + col) * 64) + q * 16);
  }

  // swizzled read base: rotation p per-lane constant (w4*128, ti*16: 0 mod 8)
  const int p = (lk + ((l15 >> 1) & 3)) & 3;
  const unsigned ra = wdest + (unsigned)(l15 * 64 + p * 16);

  // A voffsets (bytes): pixel (y0+qa, x0+qbR+2*l15), channel lk*8+k;
  // m-tile mt = +2*mt rows = mt*768B literal offset; slice step = 32*HW*4
  unsigned voff[8];
  {
    const unsigned pix = (unsigned)(((y0 + qa) * Wn + x0 + qbR + 2 * l15) * 4);
#pragma unroll
    for (int k = 0; k < 8; ++k)
      voff[k] = pix + (unsigned)((lk * 8 + k) * HW * 4);
  }
  constexpr unsigned KSTEPB = 32u * HW * 4u;   // 786,432

  floatx4 acc[4][8];
#pragma unroll
  for (int m = 0; m < 4; ++m)
#pragma unroll
    for (int i = 0; i < 8; ++i)
      acc[m][i] = {0.f, 0.f, 0.f, 0.f};
  float Araw[2][4][8];                    // raw f32 A, slot = slice&1
  half8 Afh[4];                           // converted A for current slice

  // stage h: slice sc=h>>1, group gg=h&1 (tiles gg*4..+3 -> buffer gg);
  // even stage also issues the slice's 32 scalar A loads into slot sc&1
  // and advances voff. Issue sizes: even 36, odd 4.
  auto ISSUE = [&](int h) {
    const int sc = h >> 1, gg = h & 1;
    const char* f2s = f2base + (size_t)sc * KS_STRIDE;
#pragma unroll
    for (int k = 0; k < 4; ++k)
      GLLDS(f2s + soff[gg * 4 + k], wdest + (unsigned)(gg * 4096 + k * 1024));
    if (gg == 0) {
      const int as = sc & 1;
#pragma unroll
      for (int k = 0; k < 8; ++k) {
        GLD(Araw[as][0][k], voff[k], f1b, "0")
        GLD(Araw[as][1][k], voff[k], f1b, "768")
        GLD(Araw[as][2][k], voff[k], f1b, "1536")
        GLD(Araw[as][3][k], voff[k], f1b, "2304")
        voff[k] += KSTEPB;                // next slice (data dep orders this)
      }
    }
  };
  auto COMPUTE = [&](int h) {
    const int gg = h & 1;
    if (gg == 0) {
      // A for this slice just became vmcnt-complete: convert (RNE)
      const int as = (h >> 1) & 1;
#pragma unroll
      for (int mt = 0; mt < 4; ++mt) {
        half8 v;
#pragma unroll
        for (int k = 0; k < 8; ++k)
          v[k] = (_Float16)Araw[as][mt][k];
        Afh[mt] = v;
      }
    }
    half8 bf[4];
    if (gg == 0) {
      DSREAD(bf[0], ra, "0")    DSREAD(bf[1], ra, "1024")
      DSREAD(bf[2], ra, "2048") DSREAD(bf[3], ra, "3072")
    } else {
      DSREAD(bf[0], ra, "4096") DSREAD(bf[1], ra, "5120")
      DSREAD(bf[2], ra, "6144") DSREAD(bf[3], ra, "7168")
    }
    asm volatile("s_waitcnt lgkmcnt(0)");
    __builtin_amdgcn_sched_barrier(0);    // rule 18
#pragma unroll
    for (int k = 0; k < 4; ++k) {
      const int ti = gg * 4 + k;
      acc[0][ti] = __builtin_amdgcn_mfma_f32_16x16x32_f16(Afh[0], bf[k], acc[0][ti], 0, 0, 0);
      acc[1][ti] = __builtin_amdgcn_mfma_f32_16x16x32_f16(Afh[1], bf[k], acc[1][ti], 0, 0, 0);
      acc[2][ti] = __builtin_amdgcn_mfma_f32_16x16x32_f16(Afh[2], bf[k], acc[2][ti], 0, 0, 0);
      acc[3][ti] = __builtin_amdgcn_mfma_f32_16x16x32_f16(Afh[3], bf[k], acc[3][ti], 0, 0, 0);
    }
  };

  // ---- 2-deep pipelined loop: stage h+1 in flight at compute h.
  // wait = size of I(h+1): h even -> 4, h odd -> 36; tail 0.
  ISSUE(0); ISSUE(1);
#pragma unroll
  for (int h = 0; h < 16; ++h) {
    if (h == 15)     { asm volatile("s_waitcnt vmcnt(0)"  ::: "memory"); }
    else if (h & 1)  { asm volatile("s_waitcnt vmcnt(36)" ::: "memory"); }
    else             { asm volatile("s_waitcnt vmcnt(4)"  ::: "memory"); }
    __builtin_amdgcn_sched_barrier(0);
    COMPUTE(h);
    if (h + 2 < 16) ISSUE(h + 2);
  }
  __syncthreads();                        // stage region becomes G

  // ---- deposit G (pre-scaled f16) into LDS
  _Float16* const Gh = (_Float16*)SMEM;   // G row = qb*64 + mt*16 + lk*4+rr
#pragma unroll
  for (int mt = 0; mt < 4; ++mt) {
#pragma unroll
    for (int ti = 0; ti < 8; ++ti) {
      const int n = w4 * 128 + ti * 16 + l15;
      if (n < NNc) {
#pragma unroll
        for (int rr = 0; rr < 4; ++rr)
          Gh[(qbR * 64 + mt * 16 + lk * 4 + rr) * GP + n] =
              (_Float16)(acc[mt][ti][rr] * invc);
      }
    }
  }
  __syncthreads();

  // ---- merged epilogue: full 64B lines (2 lines per (d,row))
  {
    const int niter = (ndch + 15) >> 4;   // 15 / 14
    const int dsub = t >> 5;              // 0..15
    const int alpha = (t >> 3) & 3;
    const int xq = t & 7;                 // x-quad 0..7
    const int yy = y0 + qa + 2 * alpha;
    float* ob = out + (size_t)b * ND * HW + yy * Wn + x0 + xq * 4;
    const int m0 = alpha * 16 + xq * 2;
    for (int q = 0; q < niter; ++q) {
      const int dch = q * 16 + dsub;
      if (dch < ndch) {
        const unsigned dyl = (unsigned)dch / 21u;
        const int dx = dch - (int)dyl * 21;
        const int dy = dyLo + (int)dyl;
        const int col = ((int)dyl + alpha) * NJ + xq * 2 + dx;
        floatx4 v;
        v[0] = (float)Gh[(m0) * GP + col];            // qb0, beta=2xq
        v[1] = (float)Gh[(64 + m0) * GP + col];       // qb1
        v[2] = (float)Gh[(m0 + 1) * GP + col + 1];    // qb0, beta=2xq+1
        v[3] = (float)Gh[(64 + m0 + 1) * GP + col + 1];
        __builtin_nontemporal_store(v, (floatx4*)(ob + (size_t)(dy * Dn + dx) * HW));
      }
    }
  }
}

// ---------------- fallback (round-1 kernel, original layouts) -------------
constexpr int FTY = 8, FTX = 8;
constexpr int FNTY = Hn / FTY, FNTX = Wn / FTX;
constexpr int FNJ = 24, FNTILES = 36, FGP = 580;

__global__ __launch_bounds__(256, 4)
void corr_fallback(const float* __restrict__ f1, const float* __restrict__ f2,
                   float* __restrict__ out) {
  __shared__ float G[16 * FGP];
  const int bid = blockIdx.x;
  const int cls = bid & 3;
  const int t2 = bid >> 2;
  const int tx = t2 % FNTX;
  const int t3 = t2 / FNTX;
  const int ty = t3 % FNTY;
  const int b = t3 / FNTY;
  const int qa = cls >> 1, qb = cls & 1;
  const int y0 = ty * FTY, x0 = tx * FTX;
  const int lane = threadIdx.x & 63;
  const int wave = threadIdx.x >> 6;
  const int l15 = lane & 15;
  const int lk = lane >> 4;
  const float* f1b = f1 + b * (Cn * HW);
  const float* f2b = f2 + b * (Cn * HW);
  const int ay = y0 + qa + 2 * (l15 >> 2);
  const int ax = x0 + qb + 2 * (l15 & 3);
  const float* f1p = f1b + ay * Wn + ax;
  half8 afrag[8];
#pragma unroll
  for (int ks = 0; ks < 8; ++ks)
#pragma unroll
    for (int tt = 0; tt < 8; ++tt)
      afrag[ks][tt] = (_Float16)f1p[(ks * 32 + lk * 8 + tt) * HW];
  const int nt0 = wave * (FNTILES / 4);
  for (int nt = nt0; nt < nt0 + FNTILES / 4; ++nt) {
    const unsigned n = nt * 16 + l15;
    const int i = n / (unsigned)FNJ;
    const int j = n % (unsigned)FNJ;
    const int y2 = y0 - 20 + qa + 2 * i;
    const int x2 = x0 - 20 + qb + 2 * j;
    const bool inb = (y2 >= 0) & (y2 < Hn) & (x2 >= 0) & (x2 < Wn);
    const float* f2p = f2b + (inb ? (y2 * Wn + x2) : 0);
    floatx4 acc = {0.f, 0.f, 0.f, 0.f};
#pragma unroll
    for (int ks = 0; ks < 8; ++ks) {
      half8 bfrag;
#pragma unroll
      for (int tt = 0; tt < 8; ++tt) {
        const float v = f2p[(ks * 32 + lk * 8 + tt) * HW];
        bfrag[tt] = (_Float16)(inb ? v : 0.0f);
      }
      acc = __builtin_amdgcn_mfma_f32_16x16x32_f16(afrag[ks], bfrag, acc, 0, 0, 0);
    }
#pragma unroll
    for (int r = 0; r < 4; ++r)
      G[(4 * lk + r) * FGP + n] = acc[r];
  }
  __syncthreads();
  float* outb = out + b * (ND * HW);
  const float invc = 1.0f / 256.0f;
  for (int o = threadIdx.x; o < ND * 16; o += 256) {
    const int d = o >> 4;
    const int m = o & 15;
    const int dy = (unsigned)d / 21u;
    const int dx = (unsigned)d % 21u;
    const int alpha = m >> 2, beta = m & 3;
    const float val = G[m * FGP + (alpha + dy) * FNJ + (beta + dx)] * invc;
    outb[d * HW + (y0 + qa + 2 * alpha) * Wn + (x0 + qb + 2 * beta)] = val;
  }
}

extern "C" void kernel_launch(void* const* d_in, const int* in_sizes, int n_in,
                              void* d_out, int out_size, void* d_ws, size_t ws_size,
                              hipStream_t stream) {
  const float* f1 = (const float*)d_in[0];
  const float* f2 = (const float*)d_in[1];
  float* out = (float*)d_out;
  if (ws_size >= WS_NEEDED) {
    _Float16* f2t2 = (_Float16*)d_ws;
    tconv_f2<<<dim3(F2_BLKS), dim3(256), 0, stream>>>(f2, f2t2);
    corr17<<<dim3(Bn * 2 * NTY * NTX * 2), dim3(512), 0, stream>>>(f1, f2t2, out);
  } else {
    corr_fallback<<<dim3(Bn * FNTY * FNTX * 4), dim3(256), 0, stream>>>(f1, f2, out);
  }
}

// Round 23
// 216.925 us; speedup vs baseline: 1.1523x; 1.1523x over previous
//
#include <hip/hip_runtime.h>

typedef _Float16 half8 __attribute__((ext_vector_type(8)));
typedef float floatx4 __attribute__((ext_vector_type(4)));

constexpr int Bn = 16, Cn = 256, Hn = 64, Wn = 96;
constexpr int HW = Hn * Wn;          // 6144
constexpr int Dn = 21, ND = Dn * Dn; // 441
constexpr int PH = Hn + 40;          // 104
constexpr int PW = Wn + 40;          // 136
constexpr int PHW = PH * PW;         // 14144
// pass-2 tile: 8 x 32
constexpr int TY = 8, TX = 32;
constexpr int NTY = Hn / TY;         // 8
constexpr int NTX = Wn / TX;         // 3
constexpr int NJ = (TX + 40) / 2;    // 36 window cols per parity
constexpr int GP = 506;              // G pitch f16 (NNc max 504)
// SMEM union: stage 8 waves x 8KB = 65,536 B; G 2x64x506x2 = 129,536 B
constexpr int SMEM_BYTES = 129536;   // -> 1 wg/CU (8 waves)
// f2t2 layout [b][ks:8][qb:2][py:104][cx:68][32ch f16]
constexpr size_t QB_STRIDE  = (size_t)PH * 68 * 64;      // 452,608 B
constexpr size_t KS_STRIDE  = 2 * QB_STRIDE;             // 905,216 B
constexpr size_t B2_STRIDE  = 8 * KS_STRIDE;             // 7,241,728 B

constexpr size_t F1T_BYTES = (size_t)Bn * HW * Cn * 2;   // 50,331,648
constexpr size_t F2T_BYTES = (size_t)Bn * B2_STRIDE;     // 115,867,648
constexpr size_t WS_NEEDED = F1T_BYTES + F2T_BYTES;

constexpr int F1_BLKS = Bn * (HW / 64);    // 1536
constexpr int F2_BLKS = Bn * (PHW / 64);   // 3536

// ---------------- pass 1 (merged): f32 BCHW -> f16 (two layouts) ----------
// r22 lesson: deleting f1t and reading A direct from f1 (scalar, HW-strided)
// costs far more in corr issue+amplification (+85us) than tconv saves (-35us).
__global__ __launch_bounds__(256)
void tconv_all(const float* __restrict__ f1, const float* __restrict__ f2,
               _Float16* __restrict__ f1t, _Float16* __restrict__ f2t2) {
  int blk = blockIdx.x;
  const int t = threadIdx.x;
  const int pxl = t >> 2;            // 0..63
  const int g = t & 3;
  if (blk < F1_BLKS) {
    const int b = blk / (HW / 64);
    const int px = (blk % (HW / 64)) * 64 + pxl;
    const float* src = f1 + (size_t)b * Cn * HW + px;
    _Float16* dst = f1t + ((size_t)b * HW + px) * Cn;
#pragma unroll
    for (int it = 0; it < 8; ++it) {
      const int c0 = (g + it * 4) * 8;
      half8 v;
#pragma unroll
      for (int k = 0; k < 8; ++k)
        v[k] = (_Float16)src[(size_t)(c0 + k) * HW];
      *(half8*)(dst + c0) = v;
    }
  } else {
    blk -= F1_BLKS;
    const int b = blk / (PHW / 64);
    const int ppx = (blk % (PHW / 64)) * 64 + pxl;
    const int py = ppx / PW;
    const int px = ppx - py * PW;
    const int qb = px & 1;
    const int cx = px >> 1;
    const int yy = py - 20, xx = px - 20;
    const bool valid = (yy >= 0) & (yy < Hn) & (xx >= 0) & (xx < Wn);
    const float* src = f2 + (size_t)b * Cn * HW + (valid ? (yy * Wn + xx) : 0);
#pragma unroll
    for (int h = 0; h < 2; ++h) {
      const int ks = g + h * 4;
      _Float16* dst = (_Float16*)((char*)f2t2 + (size_t)b * B2_STRIDE
                                  + (size_t)ks * KS_STRIDE + (size_t)qb * QB_STRIDE
                                  + ((size_t)py * 68 + cx) * 64);
#pragma unroll
      for (int q = 0; q < 4; ++q) {
        half8 v;
#pragma unroll
        for (int k = 0; k < 8; ++k) {
          const float f = src[(size_t)(ks * 32 + q * 8 + k) * HW];
          v[k] = (_Float16)(valid ? f : 0.0f);
        }
        *(half8*)(dst + q * 8) = v;
      }
    }
  }
}

// global->LDS DMA; lds offset raw int (SMEM at LDS offset 0), uniform (r8)
#define GLLDS(gp, lo) \
  __builtin_amdgcn_global_load_lds( \
      (const __attribute__((address_space(1))) void*)(gp), \
      (__attribute__((address_space(3))) void*)(uintptr_t)(lo), 16, 0, 0)
// asm ds_read: opaque to the LDS-DMA alias tracker (counted-vmcnt pipeline)
#define DSREAD(dst, addr, OFFSTR) \
  asm volatile("ds_read_b128 %0, %1 offset:" OFFSTR : "=v"(dst) : "v"(addr));

// ---------------- pass 2: 8x32-tile counted-vmcnt pipelined MFMA ----------
// Measured optimum (r20, reproduced r21): TX=32 (window amp 2.25x), 2-deep
// wave-private counted-vmcnt pipeline, quarter-rotation swizzle, 1 wg/CU.
// r21: 3-deep null. r22: A-direct regression. r13/14: occupancy null.
__global__ __launch_bounds__(512, 2)
void corr15(const _Float16* __restrict__ f1t, const _Float16* __restrict__ f2t2,
            float* __restrict__ out) {
  __shared__ __align__(16) char SMEM[SMEM_BYTES];

  // bijective XCD swizzle: 1536 wgs = 8 XCDs x 192 contiguous
  int bid = (int)blockIdx.x;
  bid = (bid & 7) * 192 + (bid >> 3);
  const int tx = bid % NTX;
  int tmp = bid / NTX;
  const int ty = tmp % NTY;
  tmp /= NTY;
  const int qa = tmp & 1;
  tmp >>= 1;
  const int chunk = tmp & 1;
  const int b = tmp >> 1;
  const int y0 = ty * TY, x0 = tx * TX;

  // dy chunks (11,10): dyLo 0,11; window rows = r+3
  const int r = chunk ? 10 : 11;
  const int dyLo = chunk ? 11 : 0;
  const int rows = r + 3;                 // 14 / 13
  const int NNc = rows * NJ;              // 504 / 468 window slots per qb
  const int ndch = r * Dn;                // 231 / 210

  const int t = threadIdx.x;
  const int lane = t & 63;
  const int wave = t >> 6;                // 0..7
  const int l15 = lane & 15;
  const int lk = lane >> 4;
  const int qbR = wave >> 2;              // waves 0-3 -> qb0; 4-7 -> qb1
  const int w4 = wave & 3;                // n-quarter: slots [w4*128, +128)

  const _Float16* f1b = f1t + (size_t)b * HW * Cn;
  const char* f2base = (const char*)f2t2 + (size_t)b * B2_STRIDE
                       + (size_t)qbR * QB_STRIDE;
  const float invc = 1.0f / 256.0f;

  // wave-private stage region: 8KB (2 x 4KB buffers), linear dest
  const unsigned wdest = __builtin_amdgcn_readfirstlane((unsigned)(wave * 8192));

  // DMA source offsets (ks=0): DMA u covers slots s = w4*128 + u*16 +
  // (lane>>2); position p'=lane&3 stores SOURCE quarter q=(p'-(s>>1))&3
  // (rule #21: rotation via permuted global source, LDS dest linear)
  unsigned soff[8];
#pragma unroll
  for (int u = 0; u < 8; ++u) {
    int s = w4 * 128 + u * 16 + (lane >> 2);
    if (s >= NNc) s = 0;                  // clamp: dup load, deposit guarded
    const int q = ((lane & 3) - (s >> 1)) & 3;
    const int row = s / NJ, col = s % NJ;
    const int py = y0 + qa + 2 * (row + dyLo);
    soff[u] = (unsigned)(((py * 68 + (x0 >> 1) + col) * 64) + q * 16);
  }

  // swizzled read base: rotation p per-lane constant (w4*128, ti*16: 0 mod 8)
  const int p = (lk + ((l15 >> 1) & 3)) & 3;
  const unsigned ra = wdest + (unsigned)(l15 * 64 + p * 16);

  // A fragment pointers: m-tile mt = spatial row alpha; pixel beta = l15
  const _Float16* ap0 = f1b + (size_t)((y0 + qa + 0) * Wn + x0 + qbR + 2 * l15) * Cn + lk * 8;
  const _Float16* ap1 = ap0 + (size_t)2 * Wn * Cn;
  const _Float16* ap2 = ap0 + (size_t)4 * Wn * Cn;
  const _Float16* ap3 = ap0 + (size_t)6 * Wn * Cn;

  floatx4 acc[4][8];
#pragma unroll
  for (int m = 0; m < 4; ++m)
#pragma unroll
    for (int i = 0; i < 8; ++i)
      acc[m][i] = {0.f, 0.f, 0.f, 0.f};
  half8 aA0, aA1, aA2, aA3, aB0, aB1, aB2, aB3;  // A dbuf by slice parity

  // stage h: slice sc=h>>1, group gg=h&1 (tiles gg*4..+3 -> buffer gg);
  // group 0 also issues the slice's 4 A-loads (into parity regs)
  auto ISSUE = [&](int h, half8& A0, half8& A1, half8& A2, half8& A3) {
    const int sc = h >> 1, gg = h & 1;
    const char* f2s = f2base + (size_t)sc * KS_STRIDE;
#pragma unroll
    for (int k = 0; k < 4; ++k)
      GLLDS(f2s + soff[gg * 4 + k], wdest + (unsigned)(gg * 4096 + k * 1024));
    if (gg == 0) {
      const int kb = sc * 64;
      asm volatile("global_load_dwordx4 %0, %1, off" : "=v"(A0) : "v"((const char*)ap0 + kb));
      asm volatile("global_load_dwordx4 %0, %1, off" : "=v"(A1) : "v"((const char*)ap1 + kb));
      asm volatile("global_load_dwordx4 %0, %1, off" : "=v"(A2) : "v"((const char*)ap2 + kb));
      asm volatile("global_load_dwordx4 %0, %1, off" : "=v"(A3) : "v"((const char*)ap3 + kb));
    }
  };
  auto COMPUTE = [&](int h, const half8& A0, const half8& A1,
                     const half8& A2, const half8& A3) {
    const int gg = h & 1;
    half8 bf[4];
    if (gg == 0) {
      DSREAD(bf[0], ra, "0")    DSREAD(bf[1], ra, "1024")
      DSREAD(bf[2], ra, "2048") DSREAD(bf[3], ra, "3072")
    } else {
      DSREAD(bf[0], ra, "4096") DSREAD(bf[1], ra, "5120")
      DSREAD(bf[2], ra, "6144") DSREAD(bf[3], ra, "7168")
    }
    asm volatile("s_waitcnt lgkmcnt(0)");
    __builtin_amdgcn_sched_barrier(0);    // rule 18
#pragma unroll
    for (int k = 0; k < 4; ++k) {
      const int ti = gg * 4 + k;
      acc[0][ti] = __builtin_amdgcn_mfma_f32_16x16x32_f16(A0, bf[k], acc[0][ti], 0, 0, 0);
      acc[1][ti] = __builtin_amdgcn_mfma_f32_16x16x32_f16(A1, bf[k], acc[1][ti], 0, 0, 0);
      acc[2][ti] = __builtin_amdgcn_mfma_f32_16x16x32_f16(A2, bf[k], acc[2][ti], 0, 0, 0);
      acc[3][ti] = __builtin_amdgcn_mfma_f32_16x16x32_f16(A3, bf[k], acc[3][ti], 0, 0, 0);
    }
  };

  // ---- pipelined loop: 16 stages, 2-deep, counted vmcnt, no barriers.
  // issue(h) = 4 DMA + (gg==0 ? 4 A : 0). At compute h, stage h+1 is in
  // flight: h even -> 4 outstanding, h odd -> 8.
  ISSUE(0, aA0, aA1, aA2, aA3);
  ISSUE(1, aA0, aA1, aA2, aA3);           // gg=1: no A write
#pragma unroll
  for (int h = 0; h < 16; ++h) {
    if (h == 15)     { asm volatile("s_waitcnt vmcnt(0)" ::: "memory"); }
    else if (h & 1)  { asm volatile("s_waitcnt vmcnt(8)" ::: "memory"); }
    else             { asm volatile("s_waitcnt vmcnt(4)" ::: "memory"); }
    __builtin_amdgcn_sched_barrier(0);
    if (((h >> 1) & 1) == 0) COMPUTE(h, aA0, aA1, aA2, aA3);
    else                     COMPUTE(h, aB0, aB1, aB2, aB3);
    if (h + 2 < 16) {
      if ((((h + 2) >> 1) & 1) == 0) ISSUE(h + 2, aA0, aA1, aA2, aA3);
      else                           ISSUE(h + 2, aB0, aB1, aB2, aB3);
    }
  }
  __syncthreads();                        // stage region becomes G

  // ---- deposit G (pre-scaled f16) into LDS
  _Float16* const Gh = (_Float16*)SMEM;   // G row = qb*64 + mt*16 + lk*4+rr
#pragma unroll
  for (int mt = 0; mt < 4; ++mt) {
#pragma unroll
    for (int ti = 0; ti < 8; ++ti) {
      const int n = w4 * 128 + ti * 16 + l15;
      if (n < NNc) {
#pragma unroll
        for (int rr = 0; rr < 4; ++rr)
          Gh[(qbR * 64 + mt * 16 + lk * 4 + rr) * GP + n] =
              (_Float16)(acc[mt][ti][rr] * invc);
      }
    }
  }
  __syncthreads();

  // ---- merged epilogue: full 64B lines (2 lines per (d,row))
  {
    const int niter = (ndch + 15) >> 4;   // 15 / 14
    const int dsub = t >> 5;              // 0..15
    const int alpha = (t >> 3) & 3;
    const int xq = t & 7;                 // x-quad 0..7
    const int yy = y0 + qa + 2 * alpha;
    float* ob = out + (size_t)b * ND * HW + yy * Wn + x0 + xq * 4;
    const int m0 = alpha * 16 + xq * 2;
    for (int q = 0; q < niter; ++q) {
      const int dch = q * 16 + dsub;
      if (dch < ndch) {
        const unsigned dyl = (unsigned)dch / 21u;
        const int dx = dch - (int)dyl * 21;
        const int dy = dyLo + (int)dyl;
        const int col = ((int)dyl + alpha) * NJ + xq * 2 + dx;
        floatx4 v;
        v[0] = (float)Gh[(m0) * GP + col];            // qb0, beta=2xq
        v[1] = (float)Gh[(64 + m0) * GP + col];       // qb1
        v[2] = (float)Gh[(m0 + 1) * GP + col + 1];    // qb0, beta=2xq+1
        v[3] = (float)Gh[(64 + m0 + 1) * GP + col + 1];
        __builtin_nontemporal_store(v, (floatx4*)(ob + (size_t)(dy * Dn + dx) * HW));
      }
    }
  }
}

// ---------------- fallback (round-1 kernel, original layouts) -------------
constexpr int FTY = 8, FTX = 8;
constexpr int FNTY = Hn / FTY, FNTX = Wn / FTX;
constexpr int FNJ = 24, FNTILES = 36, FGP = 580;

__global__ __launch_bounds__(256, 4)
void corr_fallback(const float* __restrict__ f1, const float* __restrict__ f2,
                   float* __restrict__ out) {
  __shared__ float G[16 * FGP];
  const int bid = blockIdx.x;
  const int cls = bid & 3;
  const int t2 = bid >> 2;
  const int tx = t2 % FNTX;
  const int t3 = t2 / FNTX;
  const int ty = t3 % FNTY;
  const int b = t3 / FNTY;
  const int qa = cls >> 1, qb = cls & 1;
  const int y0 = ty * FTY, x0 = tx * FTX;
  const int lane = threadIdx.x & 63;
  const int wave = threadIdx.x >> 6;
  const int l15 = lane & 15;
  const int lk = lane >> 4;
  const float* f1b = f1 + b * (Cn * HW);
  const float* f2b = f2 + b * (Cn * HW);
  const int ay = y0 + qa + 2 * (l15 >> 2);
  const int ax = x0 + qb + 2 * (l15 & 3);
  const float* f1p = f1b + ay * Wn + ax;
  half8 afrag[8];
#pragma unroll
  for (int ks = 0; ks < 8; ++ks)
#pragma unroll
    for (int tt = 0; tt < 8; ++tt)
      afrag[ks][tt] = (_Float16)f1p[(ks * 32 + lk * 8 + tt) * HW];
  const int nt0 = wave * (FNTILES / 4);
  for (int nt = nt0; nt < nt0 + FNTILES / 4; ++nt) {
    const unsigned n = nt * 16 + l15;
    const int i = n / (unsigned)FNJ;
    const int j = n % (unsigned)FNJ;
    const int y2 = y0 - 20 + qa + 2 * i;
    const int x2 = x0 - 20 + qb + 2 * j;
    const bool inb = (y2 >= 0) & (y2 < Hn) & (x2 >= 0) & (x2 < Wn);
    const float* f2p = f2b + (inb ? (y2 * Wn + x2) : 0);
    floatx4 acc = {0.f, 0.f, 0.f, 0.f};
#pragma unroll
    for (int ks = 0; ks < 8; ++ks) {
      half8 bfrag;
#pragma unroll
      for (int tt = 0; tt < 8; ++tt) {
        const float v = f2p[(ks * 32 + lk * 8 + tt) * HW];
        bfrag[tt] = (_Float16)(inb ? v : 0.0f);
      }
      acc = __builtin_amdgcn_mfma_f32_16x16x32_f16(afrag[ks], bfrag, acc, 0, 0, 0);
    }
#pragma unroll
    for (int r = 0; r < 4; ++r)
      G[(4 * lk + r) * FGP + n] = acc[r];
  }
  __syncthreads();
  float* outb = out + b * (ND * HW);
  const float invc = 1.0f / 256.0f;
  for (int o = threadIdx.x; o < ND * 16; o += 256) {
    const int d = o >> 4;
    const int m = o & 15;
    const int dy = (unsigned)d / 21u;
    const int dx = (unsigned)d % 21u;
    const int alpha = m >> 2, beta = m & 3;
    const float val = G[m * FGP + (alpha + dy) * FNJ + (beta + dx)] * invc;
    outb[d * HW + (y0 + qa + 2 * alpha) * Wn + (x0 + qb + 2 * beta)] = val;
  }
}

extern "C" void kernel_launch(void* const* d_in, const int* in_sizes, int n_in,
                              void* d_out, int out_size, void* d_ws, size_t ws_size,
                              hipStream_t stream) {
  const float* f1 = (const float*)d_in[0];
  const float* f2 = (const float*)d_in[1];
  float* out = (float*)d_out;
  if (ws_size >= WS_NEEDED) {
    _Float16* f1t = (_Float16*)d_ws;
    _Float16* f2t2 = (_Float16*)((char*)d_ws + F1T_BYTES);
    tconv_all<<<dim3(F1_BLKS + F2_BLKS), dim3(256), 0, stream>>>(f1, f2, f1t, f2t2);
    corr15<<<dim3(Bn * 2 * NTY * NTX * 2), dim3(512), 0, stream>>>(f1t, f2t2, out);
  } else {
    corr_fallback<<<dim3(Bn * FNTY * FNTX * 4), dim3(256), 0, stream>>>(f1, f2, out);
  }
}

// Round 24
// 188.576 us; speedup vs baseline: 1.3256x; 1.1503x over previous
//
#include <hip/hip_runtime.h>

typedef _Float16 half8 __attribute__((ext_vector_type(8)));
typedef float floatx4 __attribute__((ext_vector_type(4)));

constexpr int Bn = 16, Cn = 256, Hn = 64, Wn = 96;
constexpr int HW = Hn * Wn;          // 6144
constexpr int Dn = 21, ND = Dn * Dn; // 441
constexpr int PW = Wn + 40;          // 136 (padded x)
// pass-2 tile: 8 x 32
constexpr int TY = 8, TX = 32;
constexpr int NTY = Hn / TY;         // 8
constexpr int NTX = Wn / TX;         // 3
constexpr int NJ = (TX + 40) / 2;    // 36 window cols per parity
constexpr int GP = 506;              // G pitch f16 (NNc max 504)
// SMEM union: stage 8 waves x 8KB = 65,536 B; G 2x64x506x2 = 129,536 B
constexpr int SMEM_BYTES = 129536;   // -> 1 wg/CU (8 waves)
// f2t2 layout [b][ks:8][qb:2][vy:64][cx:68][32ch f16] -- y-pad ELIMINATED
// (out-of-y-bounds staging lanes redirect to a 64B L2-hot zero page)
constexpr int ROWB = 68 * 64;                            // 4,352 B/row
constexpr size_t QB_STRIDE = (size_t)Hn * ROWB;          // 278,528 B
constexpr size_t KS_STRIDE = 2 * QB_STRIDE;              // 557,056 B
constexpr size_t B2_STRIDE = 8 * KS_STRIDE;              // 4,456,448 B

constexpr size_t ZP_BYTES  = 256;
constexpr size_t F1T_BYTES = (size_t)Bn * HW * Cn * 2;   // 50,331,648
constexpr size_t F2T_BYTES = (size_t)Bn * B2_STRIDE;     // 71,303,168
constexpr size_t WS_NEEDED = ZP_BYTES + F1T_BYTES + F2T_BYTES;

constexpr int F1_BLKS  = Bn * (HW / 64);            // 1536
constexpr int F2V_BLKS = Bn * (Hn * PW / 64);       // 2176 (valid rows only)

// ---------------- pass 1 (merged): f32 BCHW -> f16 (two layouts) ----------
// f2t2 now stores only valid y rows (y-pad removed: was 45MB of zero writes;
// corr redirects out-of-bounds rows to the zero page). x-pad kept -- it is
// what makes staging rows contiguous (the session's biggest win, r15).
__global__ __launch_bounds__(256)
void tconv_all(const float* __restrict__ f1, const float* __restrict__ f2,
               char* __restrict__ zp, _Float16* __restrict__ f1t,
               _Float16* __restrict__ f2t2) {
  int blk = blockIdx.x;
  const int t = threadIdx.x;
  const int pxl = t >> 2;            // 0..63
  const int g = t & 3;
  if (blk < F1_BLKS) {
    if (blk == 0 && t < 16) ((unsigned*)zp)[t] = 0;   // zero page (64B)
    const int b = blk / (HW / 64);
    const int px = (blk % (HW / 64)) * 64 + pxl;
    const float* src = f1 + (size_t)b * Cn * HW + px;
    _Float16* dst = f1t + ((size_t)b * HW + px) * Cn;
#pragma unroll
    for (int it = 0; it < 8; ++it) {
      const int c0 = (g + it * 4) * 8;
      half8 v;
#pragma unroll
      for (int k = 0; k < 8; ++k)
        v[k] = (_Float16)src[(size_t)(c0 + k) * HW];
      *(half8*)(dst + c0) = v;
    }
  } else {
    blk -= F1_BLKS;
    const int b = blk / (Hn * PW / 64);
    const int pix = (blk % (Hn * PW / 64)) * 64 + pxl;   // 64x136 grid
    const int vy = pix / PW;
    const int pxp = pix - vy * PW;     // padded x in [0,136)
    const int qb = pxp & 1;
    const int cx = pxp >> 1;
    const int xx = pxp - 20;
    const bool valid = (xx >= 0) & (xx < Wn);
    const float* src = f2 + (size_t)b * Cn * HW + (valid ? (vy * Wn + xx) : 0);
#pragma unroll
    for (int h = 0; h < 2; ++h) {
      const int ks = g + h * 4;
      _Float16* dst = (_Float16*)((char*)f2t2 + (size_t)b * B2_STRIDE
                                  + (size_t)ks * KS_STRIDE + (size_t)qb * QB_STRIDE
                                  + (size_t)vy * ROWB + cx * 64);
#pragma unroll
      for (int q = 0; q < 4; ++q) {
        half8 v;
#pragma unroll
        for (int k = 0; k < 8; ++k) {
          const float f = src[(size_t)(ks * 32 + q * 8 + k) * HW];
          v[k] = (_Float16)(valid ? f : 0.0f);
        }
        *(half8*)(dst + q * 8) = v;
      }
    }
  }
}

// global->LDS DMA; lds offset raw int (SMEM at LDS offset 0), uniform (r8)
#define GLLDS(gp, lo) \
  __builtin_amdgcn_global_load_lds( \
      (const __attribute__((address_space(1))) void*)(gp), \
      (__attribute__((address_space(3))) void*)(uintptr_t)(lo), 16, 0, 0)
// asm ds_read: opaque to the LDS-DMA alias tracker (counted-vmcnt pipeline)
#define DSREAD(dst, addr, OFFSTR) \
  asm volatile("ds_read_b128 %0, %1 offset:" OFFSTR : "=v"(dst) : "v"(addr));

// ---------------- pass 2: 8x32-tile counted-vmcnt pipelined MFMA ----------
// r20 structure (measured optimum) with y-pad redirect: per-lane source
// pointer (ks=0) + per-lane ks-stride (KS_STRIDE valid / 0 -> zero page).
__global__ __launch_bounds__(512, 2)
void corr15(const _Float16* __restrict__ f1t, const _Float16* __restrict__ f2t2,
            const char* __restrict__ zp, float* __restrict__ out) {
  __shared__ __align__(16) char SMEM[SMEM_BYTES];

  // bijective XCD swizzle: 1536 wgs = 8 XCDs x 192 contiguous
  int bid = (int)blockIdx.x;
  bid = (bid & 7) * 192 + (bid >> 3);
  const int tx = bid % NTX;
  int tmp = bid / NTX;
  const int ty = tmp % NTY;
  tmp /= NTY;
  const int qa = tmp & 1;
  tmp >>= 1;
  const int chunk = tmp & 1;
  const int b = tmp >> 1;
  const int y0 = ty * TY, x0 = tx * TX;

  // dy chunks (11,10): dyLo 0,11; window rows = r+3
  const int r = chunk ? 10 : 11;
  const int dyLo = chunk ? 11 : 0;
  const int rows = r + 3;                 // 14 / 13
  const int NNc = rows * NJ;              // 504 / 468 window slots per qb
  const int ndch = r * Dn;                // 231 / 210

  const int t = threadIdx.x;
  const int lane = t & 63;
  const int wave = t >> 6;                // 0..7
  const int l15 = lane & 15;
  const int lk = lane >> 4;
  const int qbR = wave >> 2;              // waves 0-3 -> qb0; 4-7 -> qb1
  const int w4 = wave & 3;                // n-quarter: slots [w4*128, +128)

  const _Float16* f1b = f1t + (size_t)b * HW * Cn;
  const char* f2base = (const char*)f2t2 + (size_t)b * B2_STRIDE
                       + (size_t)qbR * QB_STRIDE;   // ks=0 plane
  const float invc = 1.0f / 256.0f;

  // wave-private stage region: 8KB (2 x 4KB buffers), linear dest
  const unsigned wdest = __builtin_amdgcn_readfirstlane((unsigned)(wave * 8192));

  // DMA sources (ks=0) + per-lane ks stride. DMA u covers slots
  // s = w4*128 + u*16 + (lane>>2); position p'=lane&3 stores SOURCE quarter
  // q=(p'-(s>>1))&3 (rule #21). Out-of-y-bounds row -> zero page, stride 0.
  const char* gsrc[8];
  unsigned kst[8];
#pragma unroll
  for (int u = 0; u < 8; ++u) {
    int s = w4 * 128 + u * 16 + (lane >> 2);
    if (s >= NNc) s = 0;                  // clamp: dup load, deposit guarded
    const int q = ((lane & 3) - (s >> 1)) & 3;
    const int row = s / NJ, col = s % NJ;
    const int vy = y0 + qa + 2 * (row + dyLo) - 20;
    if (vy >= 0 && vy < Hn) {
      gsrc[u] = f2base + (size_t)vy * ROWB + ((x0 >> 1) + col) * 64 + q * 16;
      kst[u] = (unsigned)KS_STRIDE;
    } else {
      gsrc[u] = zp + q * 16;              // 64B L2-hot zero line
      kst[u] = 0;
    }
  }

  // swizzled read base: rotation p per-lane constant (w4*128, ti*16: 0 mod 8)
  const int p = (lk + ((l15 >> 1) & 3)) & 3;
  const unsigned ra = wdest + (unsigned)(l15 * 64 + p * 16);

  // A fragment pointers: m-tile mt = spatial row alpha; pixel beta = l15
  const _Float16* ap0 = f1b + (size_t)((y0 + qa + 0) * Wn + x0 + qbR + 2 * l15) * Cn + lk * 8;
  const _Float16* ap1 = ap0 + (size_t)2 * Wn * Cn;
  const _Float16* ap2 = ap0 + (size_t)4 * Wn * Cn;
  const _Float16* ap3 = ap0 + (size_t)6 * Wn * Cn;

  floatx4 acc[4][8];
#pragma unroll
  for (int m = 0; m < 4; ++m)
#pragma unroll
    for (int i = 0; i < 8; ++i)
      acc[m][i] = {0.f, 0.f, 0.f, 0.f};
  half8 aA0, aA1, aA2, aA3, aB0, aB1, aB2, aB3;  // A dbuf by slice parity

  // stage h: slice sc=h>>1, group gg=h&1 (tiles gg*4..+3 -> buffer gg);
  // group 0 also issues the slice's 4 A-loads (into parity regs)
  auto ISSUE = [&](int h, half8& A0, half8& A1, half8& A2, half8& A3) {
    const int sc = h >> 1, gg = h & 1;
#pragma unroll
    for (int k = 0; k < 4; ++k) {
      const int u = gg * 4 + k;
      GLLDS(gsrc[u] + (size_t)((unsigned)sc * kst[u]),
            wdest + (unsigned)(gg * 4096 + k * 1024));
    }
    if (gg == 0) {
      const int kb = sc * 64;
      asm volatile("global_load_dwordx4 %0, %1, off" : "=v"(A0) : "v"((const char*)ap0 + kb));
      asm volatile("global_load_dwordx4 %0, %1, off" : "=v"(A1) : "v"((const char*)ap1 + kb));
      asm volatile("global_load_dwordx4 %0, %1, off" : "=v"(A2) : "v"((const char*)ap2 + kb));
      asm volatile("global_load_dwordx4 %0, %1, off" : "=v"(A3) : "v"((const char*)ap3 + kb));
    }
  };
  auto COMPUTE = [&](int h, const half8& A0, const half8& A1,
                     const half8& A2, const half8& A3) {
    const int gg = h & 1;
    half8 bf[4];
    if (gg == 0) {
      DSREAD(bf[0], ra, "0")    DSREAD(bf[1], ra, "1024")
      DSREAD(bf[2], ra, "2048") DSREAD(bf[3], ra, "3072")
    } else {
      DSREAD(bf[0], ra, "4096") DSREAD(bf[1], ra, "5120")
      DSREAD(bf[2], ra, "6144") DSREAD(bf[3], ra, "7168")
    }
    asm volatile("s_waitcnt lgkmcnt(0)");
    __builtin_amdgcn_sched_barrier(0);    // rule 18
#pragma unroll
    for (int k = 0; k < 4; ++k) {
      const int ti = gg * 4 + k;
      acc[0][ti] = __builtin_amdgcn_mfma_f32_16x16x32_f16(A0, bf[k], acc[0][ti], 0, 0, 0);
      acc[1][ti] = __builtin_amdgcn_mfma_f32_16x16x32_f16(A1, bf[k], acc[1][ti], 0, 0, 0);
      acc[2][ti] = __builtin_amdgcn_mfma_f32_16x16x32_f16(A2, bf[k], acc[2][ti], 0, 0, 0);
      acc[3][ti] = __builtin_amdgcn_mfma_f32_16x16x32_f16(A3, bf[k], acc[3][ti], 0, 0, 0);
    }
  };

  // ---- pipelined loop: 16 stages, 2-deep, counted vmcnt, no barriers.
  ISSUE(0, aA0, aA1, aA2, aA3);
  ISSUE(1, aA0, aA1, aA2, aA3);           // gg=1: no A write
#pragma unroll
  for (int h = 0; h < 16; ++h) {
    if (h == 15)     { asm volatile("s_waitcnt vmcnt(0)" ::: "memory"); }
    else if (h & 1)  { asm volatile("s_waitcnt vmcnt(8)" ::: "memory"); }
    else             { asm volatile("s_waitcnt vmcnt(4)" ::: "memory"); }
    __builtin_amdgcn_sched_barrier(0);
    if (((h >> 1) & 1) == 0) COMPUTE(h, aA0, aA1, aA2, aA3);
    else                     COMPUTE(h, aB0, aB1, aB2, aB3);
    if (h + 2 < 16) {
      if ((((h + 2) >> 1) & 1) == 0) ISSUE(h + 2, aA0, aA1, aA2, aA3);
      else                           ISSUE(h + 2, aB0, aB1, aB2, aB3);
    }
  }
  __syncthreads();                        // stage region becomes G

  // ---- deposit G (pre-scaled f16) into LDS
  _Float16* const Gh = (_Float16*)SMEM;   // G row = qb*64 + mt*16 + lk*4+rr
#pragma unroll
  for (int mt = 0; mt < 4; ++mt) {
#pragma unroll
    for (int ti = 0; ti < 8; ++ti) {
      const int n = w4 * 128 + ti * 16 + l15;
      if (n < NNc) {
#pragma unroll
        for (int rr = 0; rr < 4; ++rr)
          Gh[(qbR * 64 + mt * 16 + lk * 4 + rr) * GP + n] =
              (_Float16)(acc[mt][ti][rr] * invc);
      }
    }
  }
  __syncthreads();

  // ---- merged epilogue: full 64B lines (2 lines per (d,row))
  {
    const int niter = (ndch + 15) >> 4;   // 15 / 14
    const int dsub = t >> 5;              // 0..15
    const int alpha = (t >> 3) & 3;
    const int xq = t & 7;                 // x-quad 0..7
    const int yy = y0 + qa + 2 * alpha;
    float* ob = out + (size_t)b * ND * HW + yy * Wn + x0 + xq * 4;
    const int m0 = alpha * 16 + xq * 2;
    for (int q = 0; q < niter; ++q) {
      const int dch = q * 16 + dsub;
      if (dch < ndch) {
        const unsigned dyl = (unsigned)dch / 21u;
        const int dx = dch - (int)dyl * 21;
        const int dy = dyLo + (int)dyl;
        const int col = ((int)dyl + alpha) * NJ + xq * 2 + dx;
        floatx4 v;
        v[0] = (float)Gh[(m0) * GP + col];            // qb0, beta=2xq
        v[1] = (float)Gh[(64 + m0) * GP + col];       // qb1
        v[2] = (float)Gh[(m0 + 1) * GP + col + 1];    // qb0, beta=2xq+1
        v[3] = (float)Gh[(64 + m0 + 1) * GP + col + 1];
        __builtin_nontemporal_store(v, (floatx4*)(ob + (size_t)(dy * Dn + dx) * HW));
      }
    }
  }
}

// ---------------- fallback (round-1 kernel, original layouts) -------------
constexpr int FTY = 8, FTX = 8;
constexpr int FNTY = Hn / FTY, FNTX = Wn / FTX;
constexpr int FNJ = 24, FNTILES = 36, FGP = 580;

__global__ __launch_bounds__(256, 4)
void corr_fallback(const float* __restrict__ f1, const float* __restrict__ f2,
                   float* __restrict__ out) {
  __shared__ float G[16 * FGP];
  const int bid = blockIdx.x;
  const int cls = bid & 3;
  const int t2 = bid >> 2;
  const int tx = t2 % FNTX;
  const int t3 = t2 / FNTX;
  const int ty = t3 % FNTY;
  const int b = t3 / FNTY;
  const int qa = cls >> 1, qb = cls & 1;
  const int y0 = ty * FTY, x0 = tx * FTX;
  const int lane = threadIdx.x & 63;
  const int wave = threadIdx.x >> 6;
  const int l15 = lane & 15;
  const int lk = lane >> 4;
  const float* f1b = f1 + b * (Cn * HW);
  const float* f2b = f2 + b * (Cn * HW);
  const int ay = y0 + qa + 2 * (l15 >> 2);
  const int ax = x0 + qb + 2 * (l15 & 3);
  const float* f1p = f1b + ay * Wn + ax;
  half8 afrag[8];
#pragma unroll
  for (int ks = 0; ks < 8; ++ks)
#pragma unroll
    for (int tt = 0; tt < 8; ++tt)
      afrag[ks][tt] = (_Float16)f1p[(ks * 32 + lk * 8 + tt) * HW];
  const int nt0 = wave * (FNTILES / 4);
  for (int nt = nt0; nt < nt0 + FNTILES / 4; ++nt) {
    const unsigned n = nt * 16 + l15;
    const int i = n / (unsigned)FNJ;
    const int j = n % (unsigned)FNJ;
    const int y2 = y0 - 20 + qa + 2 * i;
    const int x2 = x0 - 20 + qb + 2 * j;
    const bool inb = (y2 >= 0) & (y2 < Hn) & (x2 >= 0) & (x2 < Wn);
    const float* f2p = f2b + (inb ? (y2 * Wn + x2) : 0);
    floatx4 acc = {0.f, 0.f, 0.f, 0.f};
#pragma unroll
    for (int ks = 0; ks < 8; ++ks) {
      half8 bfrag;
#pragma unroll
      for (int tt = 0; tt < 8; ++tt) {
        const float v = f2p[(ks * 32 + lk * 8 + tt) * HW];
        bfrag[tt] = (_Float16)(inb ? v : 0.0f);
      }
      acc = __builtin_amdgcn_mfma_f32_16x16x32_f16(afrag[ks], bfrag, acc, 0, 0, 0);
    }
#pragma unroll
    for (int r = 0; r < 4; ++r)
      G[(4 * lk + r) * FGP + n] = acc[r];
  }
  __syncthreads();
  float* outb = out + b * (ND * HW);
  const float invc = 1.0f / 256.0f;
  for (int o = threadIdx.x; o < ND * 16; o += 256) {
    const int d = o >> 4;
    const int m = o & 15;
    const int dy = (unsigned)d / 21u;
    const int dx = (unsigned)d % 21u;
    const int alpha = m >> 2, beta = m & 3;
    const float val = G[m * FGP + (alpha + dy) * FNJ + (beta + dx)] * invc;
    outb[d * HW + (y0 + qa + 2 * alpha) * Wn + (x0 + qb + 2 * beta)] = val;
  }
}

extern "C" void kernel_launch(void* const* d_in, const int* in_sizes, int n_in,
                              void* d_out, int out_size, void* d_ws, size_t ws_size,
                              hipStream_t stream) {
  const float* f1 = (const float*)d_in[0];
  const float* f2 = (const float*)d_in[1];
  float* out = (float*)d_out;
  if (ws_size >= WS_NEEDED) {
    char* zp = (char*)d_ws;
    _Float16* f1t = (_Float16*)((char*)d_ws + ZP_BYTES);
    _Float16* f2t2 = (_Float16*)((char*)d_ws + ZP_BYTES + F1T_BYTES);
    tconv_all<<<dim3(F1_BLKS + F2V_BLKS), dim3(256), 0, stream>>>(f1, f2, zp, f1t, f2t2);
    corr15<<<dim3(Bn * 2 * NTY * NTX * 2), dim3(512), 0, stream>>>(f1t, f2t2, zp, out);
  } else {
    corr_fallback<<<dim3(Bn * FNTY * FNTX * 4), dim3(256), 0, stream>>>(f1, f2, out);
  }
}